// Round 1
// baseline (670.450 us; speedup 1.0000x reference)
//
#include <hip/hip_runtime.h>
#include <hip/hip_bf16.h>

// Problem constants
#define BB 8
#define HH 64
#define WW 64
#define CC 768
#define MM (BB * HH * WW)       // 32768 pixels
#define NQKV (3 * CC)           // 2304
#define SCALE_ 0.125f           // 64^-0.5

typedef __bf16 bf16x8 __attribute__((ext_vector_type(8)));
typedef float f32x4 __attribute__((ext_vector_type(4)));

// ---------------------------------------------------------------------------
// f32 -> bf16 convert (vectorized float4 -> 4x bf16)
// ---------------------------------------------------------------------------
__global__ void cvt_kernel(const float* __restrict__ in,
                           __hip_bfloat16* __restrict__ out, int n4) {
  int i = blockIdx.x * blockDim.x + threadIdx.x;
  if (i >= n4) return;
  float4 v = reinterpret_cast<const float4*>(in)[i];
  ushort4 o;
  __hip_bfloat16 t;
  t = __float2bfloat16(v.x); o.x = __builtin_bit_cast(unsigned short, t);
  t = __float2bfloat16(v.y); o.y = __builtin_bit_cast(unsigned short, t);
  t = __float2bfloat16(v.z); o.z = __builtin_bit_cast(unsigned short, t);
  t = __float2bfloat16(v.w); o.w = __builtin_bit_cast(unsigned short, t);
  reinterpret_cast<ushort4*>(out)[i] = o;
}

// ---------------------------------------------------------------------------
// bf16 GEMM: D[M][N] = A[M][K] * Bw[N][K]^T   (all row-major, K contiguous)
// 128x128 tile, BK=32, 4 waves (2x2), mfma_f32_16x16x32_bf16.
// outB != null -> bf16 output; outF != null -> f32 output (+ optional bias).
// M % 128 == 0, N % 128 == 0, K % 32 == 0 (holds for both GEMMs here).
// ---------------------------------------------------------------------------
__global__ __launch_bounds__(256) void gemm_bf16_kernel(
    const __hip_bfloat16* __restrict__ A,
    const __hip_bfloat16* __restrict__ Bw,
    __hip_bfloat16* __restrict__ outB,
    float* __restrict__ outF,
    const float* __restrict__ bias,
    int M, int N, int K) {
  __shared__ __hip_bfloat16 lA[128 * 32];
  __shared__ __hip_bfloat16 lB[128 * 32];

  const int nBN = N >> 7;
  const int bm = blockIdx.x / nBN;
  const int bn = blockIdx.x % nBN;
  const int tid = threadIdx.x;
  const int lane = tid & 63;
  const int wv = tid >> 6;
  const int wr = wv >> 1;  // wave row (0..1), 64 rows each
  const int wc = wv & 1;   // wave col (0..1), 64 cols each

  f32x4 acc[4][4] = {};

  // staging: per call c in {0,1}: rows c*64 + wv*16 + lane/4, col (lane&3)*8
  const int srow = wv * 16 + (lane >> 2);
  const int scol = (lane & 3) * 8;
  const size_t Abase = (size_t)(bm * 128) * K;
  const size_t Bbase = (size_t)(bn * 128) * K;

  // fragment addressing: row = lane&15, k-base = (lane>>4)*8
  const int frow = lane & 15;
  const int fkb = (lane >> 4) * 8;

  for (int k0 = 0; k0 < K; k0 += 32) {
#pragma unroll
    for (int c = 0; c < 2; ++c) {
      const __hip_bfloat16* gA = A + Abase + (size_t)(c * 64 + srow) * K + k0 + scol;
      __hip_bfloat16* sA = lA + (c * 64 + wv * 16) * 32;  // wave-uniform base
      __builtin_amdgcn_global_load_lds(
          (const __attribute__((address_space(1))) void*)gA,
          (__attribute__((address_space(3))) void*)sA, 16, 0, 0);
      const __hip_bfloat16* gB = Bw + Bbase + (size_t)(c * 64 + srow) * K + k0 + scol;
      __hip_bfloat16* sB = lB + (c * 64 + wv * 16) * 32;
      __builtin_amdgcn_global_load_lds(
          (const __attribute__((address_space(1))) void*)gB,
          (__attribute__((address_space(3))) void*)sB, 16, 0, 0);
    }
    __syncthreads();

    bf16x8 af[4], bfr[4];
#pragma unroll
    for (int m = 0; m < 4; ++m)
      af[m] = *reinterpret_cast<const bf16x8*>(lA + (wr * 64 + m * 16 + frow) * 32 + fkb);
#pragma unroll
    for (int n = 0; n < 4; ++n)
      bfr[n] = *reinterpret_cast<const bf16x8*>(lB + (wc * 64 + n * 16 + frow) * 32 + fkb);
#pragma unroll
    for (int m = 0; m < 4; ++m)
#pragma unroll
      for (int n = 0; n < 4; ++n)
        acc[m][n] = __builtin_amdgcn_mfma_f32_16x16x32_bf16(af[m], bfr[n], acc[m][n], 0, 0, 0);
    __syncthreads();
  }

  // epilogue: C/D layout col = lane&15, row = (lane>>4)*4 + r  [m89]
  const int r0 = (lane >> 4) * 4;
  const int cc_ = lane & 15;
#pragma unroll
  for (int m = 0; m < 4; ++m) {
#pragma unroll
    for (int n = 0; n < 4; ++n) {
      const int grow = bm * 128 + wr * 64 + m * 16 + r0;
      const int gcol = bn * 128 + wc * 64 + n * 16 + cc_;
      if (outF) {
        const float bv = bias ? bias[gcol] : 0.f;
#pragma unroll
        for (int r = 0; r < 4; ++r)
          outF[(size_t)(grow + r) * N + gcol] = acc[m][n][r] + bv;
      } else {
#pragma unroll
        for (int r = 0; r < 4; ++r)
          outB[(size_t)(grow + r) * N + gcol] = __float2bfloat16(acc[m][n][r]);
      }
    }
  }
}

// ---------------------------------------------------------------------------
// Dilated local attention: one wave per (pixel, head); lane = head-dim (64).
// qkv: [M][2304] bf16 pixel-major. y[M][768] bf16 = attn_out + x (residual).
// OOB taps: logit stays 0 (matches zero-padding in reference softmax).
// ---------------------------------------------------------------------------
__global__ __launch_bounds__(256) void attn_kernel(
    const __hip_bfloat16* __restrict__ qkv,
    const float* __restrict__ x,
    __hip_bfloat16* __restrict__ y) {
  const int lane = threadIdx.x & 63;
  const int g = blockIdx.x * 4 + (threadIdx.x >> 6);  // (pixel, head) index
  const int head = g % 12;
  const int pixel = g / 12;
  const int h = (pixel >> 6) & 63;
  const int w = pixel & 63;
  const int grp = head >> 2;          // dilation group 0..2
  const int dil = grp + 1;            // DILATIONS = (1,2,3)
  const int chq = grp * 256 + (head & 3) * 64;

  const float qd = __bfloat162float(qkv[(size_t)pixel * 2304 + chq + lane]);

  float logit[9];
#pragma unroll
  for (int t = 0; t < 9; ++t) {
    const int di = t / 3 - 1, dj = t % 3 - 1;
    const int hh = h + di * dil, ww = w + dj * dil;
    float part = 0.f;
    if ((unsigned)hh < 64u && (unsigned)ww < 64u) {
      const int np = pixel + (di * 64 + dj) * dil;
      part = qd * __bfloat162float(qkv[(size_t)np * 2304 + 768 + chq + lane]);
    }
#pragma unroll
    for (int off = 32; off > 0; off >>= 1) part += __shfl_xor(part, off, 64);
    logit[t] = part * SCALE_;
  }

  float mx = logit[0];
#pragma unroll
  for (int t = 1; t < 9; ++t) mx = fmaxf(mx, logit[t]);
  float den = 0.f;
#pragma unroll
  for (int t = 0; t < 9; ++t) {
    logit[t] = __expf(logit[t] - mx);
    den += logit[t];
  }
  const float inv = 1.f / den;

  float acc = 0.f;
#pragma unroll
  for (int t = 0; t < 9; ++t) {
    const int di = t / 3 - 1, dj = t % 3 - 1;
    const int hh = h + di * dil, ww = w + dj * dil;
    if ((unsigned)hh < 64u && (unsigned)ww < 64u) {
      const int np = pixel + (di * 64 + dj) * dil;
      acc += logit[t] * __bfloat162float(qkv[(size_t)np * 2304 + 1536 + chq + lane]);
    }
  }
  acc *= inv;

  const size_t oi = (size_t)pixel * 768 + chq + lane;
  y[oi] = __float2bfloat16(acc + x[oi]);
}

// ---------------------------------------------------------------------------
// launch
// ---------------------------------------------------------------------------
extern "C" void kernel_launch(void* const* d_in, const int* in_sizes, int n_in,
                              void* d_out, int out_size, void* d_ws, size_t ws_size,
                              hipStream_t stream) {
  const float* x = (const float*)d_in[0];
  const float* qkv_w = (const float*)d_in[1];
  const float* proj_w = (const float*)d_in[2];
  const float* proj_b = (const float*)d_in[3];
  float* out = (float*)d_out;

  char* ws = (char*)d_ws;
  // ws layout (bytes):
  //   [0, 50331648)            xb  [M][768] bf16   -- later reused as y
  //   [50331648, 201326592)    qkvb [M][2304] bf16
  //   [201326592, 204865536)   wqkvb [2304][768] bf16
  //   [204865536, 206045184)   wprojb [768][768] bf16
  __hip_bfloat16* xb = (__hip_bfloat16*)(ws);
  __hip_bfloat16* qkvb = (__hip_bfloat16*)(ws + 50331648);
  __hip_bfloat16* wqkvb = (__hip_bfloat16*)(ws + 201326592);
  __hip_bfloat16* wprojb = (__hip_bfloat16*)(ws + 204865536);

  // converts (element counts all divisible by 4)
  cvt_kernel<<<(MM * CC / 4 + 255) / 256, 256, 0, stream>>>(x, xb, MM * CC / 4);
  cvt_kernel<<<(NQKV * CC / 4 + 255) / 256, 256, 0, stream>>>(qkv_w, wqkvb, NQKV * CC / 4);
  cvt_kernel<<<(CC * CC / 4 + 255) / 256, 256, 0, stream>>>(proj_w, wprojb, CC * CC / 4);

  // qkv GEMM: [32768 x 768] * [768 x 2304]^T -> bf16 [32768][2304]
  gemm_bf16_kernel<<<(MM / 128) * (NQKV / 128), 256, 0, stream>>>(
      xb, wqkvb, qkvb, nullptr, nullptr, MM, NQKV, CC);

  // attention + residual -> y (reuses xb buffer)
  attn_kernel<<<MM * 12 / 4, 256, 0, stream>>>(qkvb, x, xb);

  // proj GEMM: [32768 x 768] * [768 x 768]^T + bias -> f32 out
  gemm_bf16_kernel<<<(MM / 128) * (CC / 128), 256, 0, stream>>>(
      xb, wprojb, nullptr, out, proj_b, MM, CC, CC);
}

// Round 2
// 518.735 us; speedup vs baseline: 1.2925x; 1.2925x over previous
//
#include <hip/hip_runtime.h>
#include <hip/hip_bf16.h>

// Problem constants
#define CC 768
#define MM 32768                // pixels (8*64*64)
#define NQKV 2304               // 3*CC
#define SCALE_ 0.125f           // 64^-0.5

typedef __bf16 bf16x8 __attribute__((ext_vector_type(8)));
typedef float f32x4 __attribute__((ext_vector_type(4)));

static __device__ __forceinline__ float bf2f(unsigned short u) {
  return __uint_as_float(((unsigned int)u) << 16);
}
static __device__ __forceinline__ unsigned short f2bf(float f) {
  __hip_bfloat16 t = __float2bfloat16(f);
  return __builtin_bit_cast(unsigned short, t);
}

// ---------------------------------------------------------------------------
// f32 -> bf16 convert (vectorized float4 -> 4x bf16)
// ---------------------------------------------------------------------------
__global__ void cvt_kernel(const float* __restrict__ in,
                           __hip_bfloat16* __restrict__ out, int n4) {
  int i = blockIdx.x * blockDim.x + threadIdx.x;
  if (i >= n4) return;
  float4 v = reinterpret_cast<const float4*>(in)[i];
  ushort4 o;
  o.x = f2bf(v.x); o.y = f2bf(v.y); o.z = f2bf(v.z); o.w = f2bf(v.w);
  reinterpret_cast<ushort4*>(out)[i] = o;
}

// ---------------------------------------------------------------------------
// bf16 GEMM: D = A[M][K] * Bw[N][K]^T. 128x128 tile, BK=32, 4 waves (2x2).
// MODE 1: store bf16 TRANSPOSED  outT[N][M]  (8B packed stores along M)
// MODE 2: store f32 row-major out[M][N] + bias
// ---------------------------------------------------------------------------
template <int MODE>
__global__ __launch_bounds__(256) void gemm_bf16_kernel(
    const __hip_bfloat16* __restrict__ A,
    const __hip_bfloat16* __restrict__ Bw,
    void* __restrict__ outp,
    const float* __restrict__ bias,
    int M, int N, int K) {
  __shared__ __hip_bfloat16 lA[128 * 32];
  __shared__ __hip_bfloat16 lB[128 * 32];

  const int nBN = N >> 7;
  const int bm = blockIdx.x / nBN;
  const int bn = blockIdx.x % nBN;
  const int tid = threadIdx.x;
  const int lane = tid & 63;
  const int wv = tid >> 6;
  const int wr = wv >> 1;
  const int wc = wv & 1;

  f32x4 acc[4][4] = {};

  const int srow = wv * 16 + (lane >> 2);
  const int scol = (lane & 3) * 8;
  const size_t Abase = (size_t)(bm * 128) * K;
  const size_t Bbase = (size_t)(bn * 128) * K;

  const int frow = lane & 15;
  const int fkb = (lane >> 4) * 8;

  for (int k0 = 0; k0 < K; k0 += 32) {
#pragma unroll
    for (int c = 0; c < 2; ++c) {
      const __hip_bfloat16* gA = A + Abase + (size_t)(c * 64 + srow) * K + k0 + scol;
      __hip_bfloat16* sA = lA + (c * 64 + wv * 16) * 32;
      __builtin_amdgcn_global_load_lds(
          (const __attribute__((address_space(1))) void*)gA,
          (__attribute__((address_space(3))) void*)sA, 16, 0, 0);
      const __hip_bfloat16* gB = Bw + Bbase + (size_t)(c * 64 + srow) * K + k0 + scol;
      __hip_bfloat16* sB = lB + (c * 64 + wv * 16) * 32;
      __builtin_amdgcn_global_load_lds(
          (const __attribute__((address_space(1))) void*)gB,
          (__attribute__((address_space(3))) void*)sB, 16, 0, 0);
    }
    __syncthreads();

    bf16x8 af[4], bfr[4];
#pragma unroll
    for (int m = 0; m < 4; ++m)
      af[m] = *reinterpret_cast<const bf16x8*>(lA + (wr * 64 + m * 16 + frow) * 32 + fkb);
#pragma unroll
    for (int n = 0; n < 4; ++n)
      bfr[n] = *reinterpret_cast<const bf16x8*>(lB + (wc * 64 + n * 16 + frow) * 32 + fkb);
#pragma unroll
    for (int m = 0; m < 4; ++m)
#pragma unroll
      for (int n = 0; n < 4; ++n)
        acc[m][n] = __builtin_amdgcn_mfma_f32_16x16x32_bf16(af[m], bfr[n], acc[m][n], 0, 0, 0);
    __syncthreads();
  }

  // C/D layout: col = lane&15, row = (lane>>4)*4 + r   [m89]
  const int r0 = (lane >> 4) * 4;
  const int cc_ = lane & 15;
#pragma unroll
  for (int m = 0; m < 4; ++m) {
#pragma unroll
    for (int n = 0; n < 4; ++n) {
      const int grow = bm * 128 + wr * 64 + m * 16 + r0;
      const int gcol = bn * 128 + wc * 64 + n * 16 + cc_;
      if (MODE == 1) {
        __hip_bfloat16* outT = (__hip_bfloat16*)outp;
        ushort4 pk;
        pk.x = f2bf(acc[m][n][0]);
        pk.y = f2bf(acc[m][n][1]);
        pk.z = f2bf(acc[m][n][2]);
        pk.w = f2bf(acc[m][n][3]);
        *reinterpret_cast<ushort4*>(outT + (size_t)gcol * M + grow) = pk;
      } else {
        float* outF = (float*)outp;
        const float bv = bias ? bias[gcol] : 0.f;
#pragma unroll
        for (int r = 0; r < 4; ++r)
          outF[(size_t)(grow + r) * N + gcol] = acc[m][n][r] + bv;
      }
    }
  }
}

// ---------------------------------------------------------------------------
// Dilated local attention, channel-major layout.
// qkvT: [2304][M] bf16 (as ushort). thread = (pixel, head); lane-local
// head-dim reduction; all loads coalesced along pixels.
// yT out: [768][M] bf16.
// OOB taps: logit forced to 0 (participates in denominator), v-term zeroed.
// OOB reads stay inside workspace (land in adjacent planes / weight region).
// ---------------------------------------------------------------------------
__global__ __launch_bounds__(256) void attn_kernel(
    const unsigned short* __restrict__ qkvT,
    unsigned short* __restrict__ yT) {
  const int head = blockIdx.x >> 7;            // 0..11 (uniform per block)
  const int p = ((blockIdx.x & 127) << 8) + threadIdx.x;  // pixel
  const int h = (p >> 6) & 63;
  const int w = p & 63;
  const int grp = head >> 2;
  const int dil = grp + 1;                     // DILATIONS = (1,2,3)
  const int chq = grp * 256 + (head & 3) * 64;

  int voff[9];
  bool valid[9];
#pragma unroll
  for (int t = 0; t < 9; ++t) {
    const int di = t / 3 - 1, dj = t % 3 - 1;
    valid[t] = ((unsigned)(h + di * dil) < 64u) && ((unsigned)(w + dj * dil) < 64u);
    voff[t] = p + (di * 64 + dj) * dil + 256;  // +256 bias keeps index >= 0
  }
  const int voffq = p + 256;

  const unsigned short* qb = qkvT + (size_t)chq * MM - 256;
  const unsigned short* kb = qkvT + (size_t)(768 + chq) * MM - 256;

  float l[9] = {};
#pragma unroll 4
  for (int c = 0; c < 64; ++c) {
    const float qv = bf2f(qb[voffq]);
#pragma unroll
    for (int t = 0; t < 9; ++t)
      l[t] = fmaf(qv, bf2f(kb[voff[t]]), l[t]);
    qb += MM;
    kb += MM;
  }

#pragma unroll
  for (int t = 0; t < 9; ++t) l[t] = valid[t] ? l[t] * SCALE_ : 0.f;
  float mx = l[0];
#pragma unroll
  for (int t = 1; t < 9; ++t) mx = fmaxf(mx, l[t]);
  float den = 0.f;
#pragma unroll
  for (int t = 0; t < 9; ++t) {
    const float e = __expf(l[t] - mx);
    den += e;                                  // invalid taps count in denom
    l[t] = valid[t] ? e : 0.f;                 // but contribute 0 to numerator
  }
  const float inv = 1.f / den;

  const unsigned short* vb = qkvT + (size_t)(1536 + chq) * MM - 256;
  unsigned short* yb = yT + (size_t)chq * MM + p;
#pragma unroll 4
  for (int c = 0; c < 64; ++c) {
    float acc = 0.f;
#pragma unroll
    for (int t = 0; t < 9; ++t)
      acc = fmaf(l[t], bf2f(vb[voff[t]]), acc);
    vb += MM;
    *yb = f2bf(acc * inv);
    yb += MM;
  }
}

// ---------------------------------------------------------------------------
// y[p][c] = bf16( yT[c][p] + x[p][c] )  — 32x32 LDS tile transpose + residual
// ---------------------------------------------------------------------------
__global__ __launch_bounds__(256) void tr_add_kernel(
    const unsigned short* __restrict__ yT,
    const float* __restrict__ x,
    unsigned short* __restrict__ y) {
  __shared__ unsigned short s[32][33];
  const int tx = threadIdx.x & 31;
  const int ty = threadIdx.x >> 5;
  const int pt = (blockIdx.x & 1023) << 5;     // pixel tile base
  const int ct = (blockIdx.x >> 10) << 5;      // channel tile base
#pragma unroll
  for (int k = 0; k < 4; ++k) {
    const int c = ct + ty + k * 8;
    s[ty + k * 8][tx] = yT[(size_t)c * MM + pt + tx];
  }
  __syncthreads();
#pragma unroll
  for (int k = 0; k < 4; ++k) {
    const int p = pt + ty + k * 8;
    const int c = ct + tx;
    const float v = bf2f(s[tx][ty + k * 8]) + x[(size_t)p * CC + c];
    y[(size_t)p * CC + c] = f2bf(v);
  }
}

// ---------------------------------------------------------------------------
// launch
// ---------------------------------------------------------------------------
extern "C" void kernel_launch(void* const* d_in, const int* in_sizes, int n_in,
                              void* d_out, int out_size, void* d_ws, size_t ws_size,
                              hipStream_t stream) {
  const float* x = (const float*)d_in[0];
  const float* qkv_w = (const float*)d_in[1];
  const float* proj_w = (const float*)d_in[2];
  const float* proj_b = (const float*)d_in[3];
  float* out = (float*)d_out;

  char* ws = (char*)d_ws;
  // ws layout (bytes), total 206,045,184 (same footprint as round 1):
  //   [0, 50331648)            xb [M][768] bf16   -> reused as yT [768][M] after GEMM1
  //   [50331648, 201326592)    qkvT [2304][M] bf16 -> first 50MB reused as y [M][768]
  //   [201326592, 204865536)   wqkvb [2304][768] bf16 (also absorbs tiny OOB tap reads)
  //   [204865536, 206045184)   wprojb [768][768] bf16
  __hip_bfloat16* xb = (__hip_bfloat16*)(ws);
  __hip_bfloat16* qkvT = (__hip_bfloat16*)(ws + 50331648);
  __hip_bfloat16* wqkvb = (__hip_bfloat16*)(ws + 201326592);
  __hip_bfloat16* wprojb = (__hip_bfloat16*)(ws + 204865536);
  __hip_bfloat16* yTbuf = xb;                       // after GEMM1, xb is free
  __hip_bfloat16* ybuf = qkvT;                      // after attn, qkvT is free

  cvt_kernel<<<(MM * CC / 4 + 255) / 256, 256, 0, stream>>>(x, xb, MM * CC / 4);
  cvt_kernel<<<(NQKV * CC / 4 + 255) / 256, 256, 0, stream>>>(qkv_w, wqkvb, NQKV * CC / 4);
  cvt_kernel<<<(CC * CC / 4 + 255) / 256, 256, 0, stream>>>(proj_w, wprojb, CC * CC / 4);

  // qkv GEMM -> channel-major qkvT [2304][M]
  gemm_bf16_kernel<1><<<(MM / 128) * (NQKV / 128), 256, 0, stream>>>(
      xb, wqkvb, (void*)qkvT, nullptr, MM, NQKV, CC);

  // attention -> yT [768][M]
  attn_kernel<<<12 * 128, 256, 0, stream>>>(
      (const unsigned short*)qkvT, (unsigned short*)yTbuf);

  // transpose + residual -> y [M][768] bf16
  tr_add_kernel<<<1024 * 24, 256, 0, stream>>>(
      (const unsigned short*)yTbuf, x, (unsigned short*)ybuf);

  // proj GEMM -> f32 out [M][768] + bias
  gemm_bf16_kernel<2><<<(MM / 128) * (CC / 128), 256, 0, stream>>>(
      ybuf, wprojb, (void*)out, proj_b, MM, CC, CC);
}

// Round 3
// 436.950 us; speedup vs baseline: 1.5344x; 1.1872x over previous
//
#include <hip/hip_runtime.h>
#include <hip/hip_bf16.h>

// Problem constants
#define CC 768
#define MM 32768                // pixels (8*64*64)
#define NQKV 2304               // 3*CC
#define SCALE_ 0.125f           // 64^-0.5

typedef __bf16 bf16x8 __attribute__((ext_vector_type(8)));
typedef float f32x4 __attribute__((ext_vector_type(4)));
typedef unsigned short ushort8_t __attribute__((ext_vector_type(8)));

static __device__ __forceinline__ float bf2f(unsigned short u) {
  return __uint_as_float(((unsigned int)u) << 16);
}
static __device__ __forceinline__ unsigned short f2bf(float f) {
  __hip_bfloat16 t = __float2bfloat16(f);
  return __builtin_bit_cast(unsigned short, t);
}

// ---------------------------------------------------------------------------
// f32 -> bf16 convert (vectorized float4 -> 4x bf16)
// ---------------------------------------------------------------------------
__global__ void cvt_kernel(const float* __restrict__ in,
                           __hip_bfloat16* __restrict__ out, int n4) {
  int i = blockIdx.x * blockDim.x + threadIdx.x;
  if (i >= n4) return;
  float4 v = reinterpret_cast<const float4*>(in)[i];
  ushort4 o;
  o.x = f2bf(v.x); o.y = f2bf(v.y); o.z = f2bf(v.z); o.w = f2bf(v.w);
  reinterpret_cast<ushort4*>(out)[i] = o;
}

// ---------------------------------------------------------------------------
// bf16 GEMM: D = A[M][K] * Bw[N][K]^T. 128x128 tile, BK=32, 4 waves (2x2).
// 2-phase prefetch double-buffer (T3-minimum): STAGE(t+1) issued BEFORE
// ds_read+MFMA of tile t; ONE barrier per iter (implicit vmcnt/lgkm drain).
// XCD-aware block swizzle (grid % 8 == 0 for both call sites).
// MODE 1: store bf16 TRANSPOSED outT[N][M] (8B packed stores along M)
// MODE 2: store f32 row-major out[M][N] + bias
// ---------------------------------------------------------------------------
template <int MODE>
__global__ __launch_bounds__(256) void gemm_bf16_kernel(
    const __hip_bfloat16* __restrict__ A,
    const __hip_bfloat16* __restrict__ Bw,
    void* __restrict__ outp,
    const float* __restrict__ bias,
    int M, int N, int K) {
  __shared__ __hip_bfloat16 lA[2][128 * 32];
  __shared__ __hip_bfloat16 lB[2][128 * 32];

  const int nBN = N >> 7;
  const int cpx = gridDim.x >> 3;                 // chunks per XCD
  const int bid = ((int)blockIdx.x & 7) * cpx + ((int)blockIdx.x >> 3);
  const int bm = bid / nBN;
  const int bn = bid % nBN;
  const int tid = threadIdx.x;
  const int lane = tid & 63;
  const int wv = tid >> 6;
  const int wr = wv >> 1;
  const int wc = wv & 1;

  f32x4 acc[4][4] = {};

  const int srow = wv * 16 + (lane >> 2);
  const int scol = (lane & 3) * 8;
  const size_t Abase = (size_t)(bm * 128) * K;
  const size_t Bbase = (size_t)(bn * 128) * K;

  const int frow = lane & 15;
  const int fkb = (lane >> 4) * 8;

  auto stage = [&](int buf, int k0) {
#pragma unroll
    for (int c = 0; c < 2; ++c) {
      const __hip_bfloat16* gA = A + Abase + (size_t)(c * 64 + srow) * K + k0 + scol;
      __hip_bfloat16* sA = &lA[buf][(c * 64 + wv * 16) * 32];
      __builtin_amdgcn_global_load_lds(
          (const __attribute__((address_space(1))) void*)gA,
          (__attribute__((address_space(3))) void*)sA, 16, 0, 0);
      const __hip_bfloat16* gB = Bw + Bbase + (size_t)(c * 64 + srow) * K + k0 + scol;
      __hip_bfloat16* sB = &lB[buf][(c * 64 + wv * 16) * 32];
      __builtin_amdgcn_global_load_lds(
          (const __attribute__((address_space(1))) void*)gB,
          (__attribute__((address_space(3))) void*)sB, 16, 0, 0);
    }
  };

  const int nt = K >> 5;
  stage(0, 0);
  __syncthreads();                                // drains vmcnt -> buf0 ready

  int cur = 0;
  for (int t = 0; t < nt; ++t) {
    if (t + 1 < nt) stage(cur ^ 1, (t + 1) << 5); // prefetch overlaps compute

    bf16x8 af[4], bfr[4];
#pragma unroll
    for (int m = 0; m < 4; ++m)
      af[m] = *reinterpret_cast<const bf16x8*>(&lA[cur][(wr * 64 + m * 16 + frow) * 32 + fkb]);
#pragma unroll
    for (int n = 0; n < 4; ++n)
      bfr[n] = *reinterpret_cast<const bf16x8*>(&lB[cur][(wc * 64 + n * 16 + frow) * 32 + fkb]);
#pragma unroll
    for (int m = 0; m < 4; ++m)
#pragma unroll
      for (int n = 0; n < 4; ++n)
        acc[m][n] = __builtin_amdgcn_mfma_f32_16x16x32_bf16(af[m], bfr[n], acc[m][n], 0, 0, 0);

    __syncthreads();                              // next buf staged + reads done
    cur ^= 1;
  }

  // C/D layout: col = lane&15, row = (lane>>4)*4 + r   [m89]
  const int r0 = (lane >> 4) * 4;
  const int cc_ = lane & 15;
#pragma unroll
  for (int m = 0; m < 4; ++m) {
#pragma unroll
    for (int n = 0; n < 4; ++n) {
      const int grow = bm * 128 + wr * 64 + m * 16 + r0;
      const int gcol = bn * 128 + wc * 64 + n * 16 + cc_;
      if (MODE == 1) {
        __hip_bfloat16* outT = (__hip_bfloat16*)outp;
        ushort4 pk;
        pk.x = f2bf(acc[m][n][0]);
        pk.y = f2bf(acc[m][n][1]);
        pk.z = f2bf(acc[m][n][2]);
        pk.w = f2bf(acc[m][n][3]);
        *reinterpret_cast<ushort4*>(outT + (size_t)gcol * M + grow) = pk;
      } else {
        float* outF = (float*)outp;
        const float bv = bias ? bias[gcol] : 0.f;
#pragma unroll
        for (int r = 0; r < 4; ++r)
          outF[(size_t)(grow + r) * N + gcol] = acc[m][n][r] + bv;
      }
    }
  }
}

// ---------------------------------------------------------------------------
// Dilated local attention, channel-major input, PIXEL-MAJOR fused output:
// y[p][c] = bf16(attn_out + x[p][c])  (residual fused; tr_add eliminated).
// qkvT: [2304][M] bf16. thread = (pixel, head); lane-local head-dim loop;
// per-thread 64 outputs kept in registers (statically unrolled), written as
// 8x16B contiguous stores.
// OOB taps: logit 0 in denominator, 0 in numerator (matches zero-pad ref).
// OOB reads land inside workspace (adjacent planes / weight region).
// ---------------------------------------------------------------------------
__global__ __launch_bounds__(256) void attn_kernel(
    const unsigned short* __restrict__ qkvT,
    const float* __restrict__ x,
    unsigned short* __restrict__ y) {
  const int head = blockIdx.x >> 7;            // 0..11 (uniform per block)
  const int p = ((blockIdx.x & 127) << 8) + threadIdx.x;  // pixel
  const int h = (p >> 6) & 63;
  const int w = p & 63;
  const int grp = head >> 2;
  const int dil = grp + 1;                     // DILATIONS = (1,2,3)
  const int chq = grp * 256 + (head & 3) * 64;

  int voff[9];
  bool valid[9];
#pragma unroll
  for (int t = 0; t < 9; ++t) {
    const int di = t / 3 - 1, dj = t % 3 - 1;
    valid[t] = ((unsigned)(h + di * dil) < 64u) && ((unsigned)(w + dj * dil) < 64u);
    voff[t] = p + (di * 64 + dj) * dil + 256;  // +256 bias keeps index >= 0
  }
  const int voffq = p + 256;

  const unsigned short* qb = qkvT + (size_t)chq * MM - 256;
  const unsigned short* kb = qkvT + (size_t)(768 + chq) * MM - 256;

  float l[9] = {};
#pragma unroll 4
  for (int c = 0; c < 64; ++c) {
    const float qv = bf2f(qb[voffq]);
#pragma unroll
    for (int t = 0; t < 9; ++t)
      l[t] = fmaf(qv, bf2f(kb[voff[t]]), l[t]);
    qb += MM;
    kb += MM;
  }

#pragma unroll
  for (int t = 0; t < 9; ++t) l[t] = valid[t] ? l[t] * SCALE_ : 0.f;
  float mx = l[0];
#pragma unroll
  for (int t = 1; t < 9; ++t) mx = fmaxf(mx, l[t]);
  float den = 0.f;
#pragma unroll
  for (int t = 0; t < 9; ++t) {
    const float e = __expf(l[t] - mx);
    den += e;                                  // invalid taps count in denom
    l[t] = valid[t] ? e : 0.f;                 // but contribute 0 to numerator
  }
  const float inv = 1.f / den;

  const unsigned short* vb = qkvT + (size_t)(1536 + chq) * MM - 256;
  float vout[64];
#pragma unroll
  for (int c = 0; c < 64; ++c) {               // fully unrolled: static idx
    float acc = 0.f;
#pragma unroll
    for (int t = 0; t < 9; ++t)
      acc = fmaf(l[t], bf2f(vb[voff[t]]), acc);
    vb += MM;
    vout[c] = acc * inv;
  }

  // residual + pack + store: 8 x 16B contiguous per thread
  const float4* xr = reinterpret_cast<const float4*>(x + (size_t)p * CC + chq);
  ushort8_t* yr = reinterpret_cast<ushort8_t*>(y + (size_t)p * CC + chq);
#pragma unroll
  for (int k = 0; k < 8; ++k) {
    const float4 xa = xr[2 * k];
    const float4 xb4 = xr[2 * k + 1];
    ushort8_t o;
    o[0] = f2bf(vout[8 * k + 0] + xa.x);
    o[1] = f2bf(vout[8 * k + 1] + xa.y);
    o[2] = f2bf(vout[8 * k + 2] + xa.z);
    o[3] = f2bf(vout[8 * k + 3] + xa.w);
    o[4] = f2bf(vout[8 * k + 4] + xb4.x);
    o[5] = f2bf(vout[8 * k + 5] + xb4.y);
    o[6] = f2bf(vout[8 * k + 6] + xb4.z);
    o[7] = f2bf(vout[8 * k + 7] + xb4.w);
    yr[k] = o;
  }
}

// ---------------------------------------------------------------------------
// launch
// ---------------------------------------------------------------------------
extern "C" void kernel_launch(void* const* d_in, const int* in_sizes, int n_in,
                              void* d_out, int out_size, void* d_ws, size_t ws_size,
                              hipStream_t stream) {
  const float* x = (const float*)d_in[0];
  const float* qkv_w = (const float*)d_in[1];
  const float* proj_w = (const float*)d_in[2];
  const float* proj_b = (const float*)d_in[3];
  float* out = (float*)d_out;

  char* ws = (char*)d_ws;
  // ws layout (bytes), total 206,045,184:
  //   [0, 50331648)            xb [M][768] bf16  -> reused as y [M][768] bf16
  //   [50331648, 201326592)    qkvT [2304][M] bf16
  //   [201326592, 204865536)   wqkvb [2304][768] bf16 (absorbs OOB tap reads)
  //   [204865536, 206045184)   wprojb [768][768] bf16
  __hip_bfloat16* xb = (__hip_bfloat16*)(ws);
  __hip_bfloat16* qkvT = (__hip_bfloat16*)(ws + 50331648);
  __hip_bfloat16* wqkvb = (__hip_bfloat16*)(ws + 201326592);
  __hip_bfloat16* wprojb = (__hip_bfloat16*)(ws + 204865536);
  __hip_bfloat16* ybuf = xb;                   // after GEMM1 consumed xb

  cvt_kernel<<<(MM * CC / 4 + 255) / 256, 256, 0, stream>>>(x, xb, MM * CC / 4);
  cvt_kernel<<<(NQKV * CC / 4 + 255) / 256, 256, 0, stream>>>(qkv_w, wqkvb, NQKV * CC / 4);
  cvt_kernel<<<(CC * CC / 4 + 255) / 256, 256, 0, stream>>>(proj_w, wprojb, CC * CC / 4);

  // qkv GEMM -> channel-major qkvT [2304][M]   (grid 4608 % 8 == 0)
  gemm_bf16_kernel<1><<<(MM / 128) * (NQKV / 128), 256, 0, stream>>>(
      xb, wqkvb, (void*)qkvT, nullptr, MM, NQKV, CC);

  // attention + residual -> y [M][768] bf16 (pixel-major, fused transpose)
  attn_kernel<<<12 * 128, 256, 0, stream>>>(
      (const unsigned short*)qkvT, x, (unsigned short*)ybuf);

  // proj GEMM -> f32 out [M][768] + bias      (grid 1536 % 8 == 0)
  gemm_bf16_kernel<2><<<(MM / 128) * (CC / 128), 256, 0, stream>>>(
      ybuf, wprojb, (void*)out, proj_b, MM, CC, CC);
}

// Round 4
// 417.141 us; speedup vs baseline: 1.6073x; 1.0475x over previous
//
#include <hip/hip_runtime.h>
#include <hip/hip_bf16.h>

// Problem constants
#define CC 768
#define MM 32768                // pixels (8*64*64)
#define NQKV 2304               // 3*CC
#define SCALE_ 0.125f           // 64^-0.5

typedef __bf16 bf16x8 __attribute__((ext_vector_type(8)));
typedef float f32x4 __attribute__((ext_vector_type(4)));
typedef unsigned short ushort8_t __attribute__((ext_vector_type(8)));

static __device__ __forceinline__ float bf2f(unsigned short u) {
  return __uint_as_float(((unsigned int)u) << 16);
}
static __device__ __forceinline__ unsigned short f2bf(float f) {
  __hip_bfloat16 t = __float2bfloat16(f);
  return __builtin_bit_cast(unsigned short, t);
}

// ---------------------------------------------------------------------------
// f32 -> bf16 convert (vectorized float4 -> 4x bf16)
// ---------------------------------------------------------------------------
__global__ void cvt_kernel(const float* __restrict__ in,
                           __hip_bfloat16* __restrict__ out, int n4) {
  int i = blockIdx.x * blockDim.x + threadIdx.x;
  if (i >= n4) return;
  float4 v = reinterpret_cast<const float4*>(in)[i];
  ushort4 o;
  o.x = f2bf(v.x); o.y = f2bf(v.y); o.z = f2bf(v.z); o.w = f2bf(v.w);
  reinterpret_cast<ushort4*>(out)[i] = o;
}

// ---------------------------------------------------------------------------
// bf16 GEMM: D = A[M][K] * Bw[N][K]^T. 128x128 tile, BK=32, 4 waves (2x2).
// Depth-2 counted-vmcnt pipeline (T3+T4): 3 LDS buffer sets; per iter
//   s_waitcnt vmcnt(4) -> s_barrier -> ds_read buf[t%3] -> stage t+2 -> MFMA
// vmcnt never drains to 0 in the main loop.
// LDS bank-conflict fix (rule #21): linear LDS dest, column-block permuted
// GLOBAL source (blk = (l&3)^((l>>3)&3)), matching XOR on the read side ->
// each 16-lane read group covers 8 bank-quads = 2-way = free.
// XCD-aware block swizzle (grid % 8 == 0 at both call sites).
// MODE 1: store bf16 TRANSPOSED outT[N][M]; MODE 2: f32 out[M][N] + bias.
// ---------------------------------------------------------------------------
template <int MODE>
__global__ __launch_bounds__(256) void gemm_bf16_kernel(
    const __hip_bfloat16* __restrict__ A,
    const __hip_bfloat16* __restrict__ Bw,
    void* __restrict__ outp,
    const float* __restrict__ bias,
    int M, int N, int K) {
  __shared__ __hip_bfloat16 lA[3][128 * 32];
  __shared__ __hip_bfloat16 lB[3][128 * 32];

  const int nBN = N >> 7;
  const int cpx = gridDim.x >> 3;                 // chunks per XCD (grid%8==0)
  const int bid = ((int)blockIdx.x & 7) * cpx + ((int)blockIdx.x >> 3);
  const int bm = bid / nBN;
  const int bn = bid % nBN;
  const int tid = threadIdx.x;
  const int lane = tid & 63;
  const int wv = tid >> 6;
  const int wr = wv >> 1;
  const int wc = wv & 1;

  f32x4 acc[4][4] = {};

  // staging: lane l -> LDS linear slot (row = wv*16 + l>>2, 16B slot l&3);
  // that slot must hold global column-block (l&3) ^ ((l>>3)&3)  [swizzle]
  const int srow = wv * 16 + (lane >> 2);
  const int scol = ((lane & 3) ^ ((lane >> 3) & 3)) * 8;   // elements
  const size_t Abase = (size_t)(bm * 128) * K;
  const size_t Bbase = (size_t)(bn * 128) * K;

  // fragment read: row = lane&15, k-block g = lane>>4 stored at
  // slot g ^ ((row>>1)&3) within the row
  const int frow = lane & 15;
  const int g = lane >> 4;
  const int fcol = (g ^ ((frow >> 1) & 3)) * 8;            // elements

  auto stage = [&](int buf, int t) {
    const int k0 = t << 5;
#pragma unroll
    for (int c = 0; c < 2; ++c) {
      const __hip_bfloat16* gA = A + Abase + (size_t)(c * 64 + srow) * K + k0 + scol;
      __hip_bfloat16* sA = &lA[buf][(c * 64 + wv * 16) * 32];
      __builtin_amdgcn_global_load_lds(
          (const __attribute__((address_space(1))) void*)gA,
          (__attribute__((address_space(3))) void*)sA, 16, 0, 0);
      const __hip_bfloat16* gB = Bw + Bbase + (size_t)(c * 64 + srow) * K + k0 + scol;
      __hip_bfloat16* sB = &lB[buf][(c * 64 + wv * 16) * 32];
      __builtin_amdgcn_global_load_lds(
          (const __attribute__((address_space(1))) void*)gB,
          (__attribute__((address_space(3))) void*)sB, 16, 0, 0);
    }
  };

  const int nt = K >> 5;                     // 24 here
  stage(0, 0);
  if (nt > 1) stage(1, 1);

  int rd = 0;                                // t % 3
  int st = 2;                                // (t+2) % 3
  for (int t = 0; t < nt; ++t) {
    // tile t's 4 loads done; tile t+1's (if any) may remain in flight
    if (t + 1 < nt) asm volatile("s_waitcnt vmcnt(4)" ::: "memory");
    else            asm volatile("s_waitcnt vmcnt(0)" ::: "memory");
    __builtin_amdgcn_s_barrier();
    asm volatile("" ::: "memory");

    bf16x8 af[4], bfr[4];
#pragma unroll
    for (int m = 0; m < 4; ++m)
      af[m] = *reinterpret_cast<const bf16x8*>(&lA[rd][(wr * 64 + m * 16 + frow) * 32 + fcol]);
#pragma unroll
    for (int n = 0; n < 4; ++n)
      bfr[n] = *reinterpret_cast<const bf16x8*>(&lB[rd][(wc * 64 + n * 16 + frow) * 32 + fcol]);

    if (t + 2 < nt) stage(st, t + 2);        // overwrites buf[(t-1)%3]: its
                                             // readers finished before the
                                             // barrier above
#pragma unroll
    for (int m = 0; m < 4; ++m)
#pragma unroll
      for (int n = 0; n < 4; ++n)
        acc[m][n] = __builtin_amdgcn_mfma_f32_16x16x32_bf16(af[m], bfr[n], acc[m][n], 0, 0, 0);

    rd = (rd == 2) ? 0 : rd + 1;
    st = (st == 2) ? 0 : st + 1;
  }

  // C/D layout: col = lane&15, row = (lane>>4)*4 + r   [m89]
  const int r0 = (lane >> 4) * 4;
  const int cc_ = lane & 15;
#pragma unroll
  for (int m = 0; m < 4; ++m) {
#pragma unroll
    for (int n = 0; n < 4; ++n) {
      const int grow = bm * 128 + wr * 64 + m * 16 + r0;
      const int gcol = bn * 128 + wc * 64 + n * 16 + cc_;
      if (MODE == 1) {
        __hip_bfloat16* outT = (__hip_bfloat16*)outp;
        ushort4 pk;
        pk.x = f2bf(acc[m][n][0]);
        pk.y = f2bf(acc[m][n][1]);
        pk.z = f2bf(acc[m][n][2]);
        pk.w = f2bf(acc[m][n][3]);
        *reinterpret_cast<ushort4*>(outT + (size_t)gcol * M + grow) = pk;
      } else {
        float* outF = (float*)outp;
        const float bv = bias ? bias[gcol] : 0.f;
#pragma unroll
        for (int r = 0; r < 4; ++r)
          outF[(size_t)(grow + r) * N + gcol] = acc[m][n][r] + bv;
      }
    }
  }
}

// ---------------------------------------------------------------------------
// Dilated local attention, channel-major input, PIXEL-MAJOR fused output:
// y[p][c] = bf16(attn_out + x[p][c])  (residual fused).
// qkvT: [2304][M] bf16. thread = (pixel, head); lane-local head-dim loop;
// 64 outputs in registers (statically unrolled), 8x16B contiguous stores.
// OOB taps: logit 0 in denominator, 0 in numerator (matches zero-pad ref).
// OOB reads land inside workspace (adjacent planes / weight region).
// ---------------------------------------------------------------------------
__global__ __launch_bounds__(256) void attn_kernel(
    const unsigned short* __restrict__ qkvT,
    const float* __restrict__ x,
    unsigned short* __restrict__ y) {
  const int head = blockIdx.x >> 7;            // 0..11 (uniform per block)
  const int p = ((blockIdx.x & 127) << 8) + threadIdx.x;  // pixel
  const int h = (p >> 6) & 63;
  const int w = p & 63;
  const int grp = head >> 2;
  const int dil = grp + 1;                     // DILATIONS = (1,2,3)
  const int chq = grp * 256 + (head & 3) * 64;

  int voff[9];
  bool valid[9];
#pragma unroll
  for (int t = 0; t < 9; ++t) {
    const int di = t / 3 - 1, dj = t % 3 - 1;
    valid[t] = ((unsigned)(h + di * dil) < 64u) && ((unsigned)(w + dj * dil) < 64u);
    voff[t] = p + (di * 64 + dj) * dil + 256;  // +256 bias keeps index >= 0
  }
  const int voffq = p + 256;

  const unsigned short* qb = qkvT + (size_t)chq * MM - 256;
  const unsigned short* kb = qkvT + (size_t)(768 + chq) * MM - 256;

  float l[9] = {};
#pragma unroll 4
  for (int c = 0; c < 64; ++c) {
    const float qv = bf2f(qb[voffq]);
#pragma unroll
    for (int t = 0; t < 9; ++t)
      l[t] = fmaf(qv, bf2f(kb[voff[t]]), l[t]);
    qb += MM;
    kb += MM;
  }

#pragma unroll
  for (int t = 0; t < 9; ++t) l[t] = valid[t] ? l[t] * SCALE_ : 0.f;
  float mx = l[0];
#pragma unroll
  for (int t = 1; t < 9; ++t) mx = fmaxf(mx, l[t]);
  float den = 0.f;
#pragma unroll
  for (int t = 0; t < 9; ++t) {
    const float e = __expf(l[t] - mx);
    den += e;                                  // invalid taps count in denom
    l[t] = valid[t] ? e : 0.f;                 // but contribute 0 to numerator
  }
  const float inv = 1.f / den;

  const unsigned short* vb = qkvT + (size_t)(1536 + chq) * MM - 256;
  float vout[64];
#pragma unroll
  for (int c = 0; c < 64; ++c) {               // fully unrolled: static idx
    float acc = 0.f;
#pragma unroll
    for (int t = 0; t < 9; ++t)
      acc = fmaf(l[t], bf2f(vb[voff[t]]), acc);
    vb += MM;
    vout[c] = acc * inv;
  }

  // residual + pack + store: 8 x 16B contiguous per thread
  const float4* xr = reinterpret_cast<const float4*>(x + (size_t)p * CC + chq);
  ushort8_t* yr = reinterpret_cast<ushort8_t*>(y + (size_t)p * CC + chq);
#pragma unroll
  for (int k = 0; k < 8; ++k) {
    const float4 xa = xr[2 * k];
    const float4 xb4 = xr[2 * k + 1];
    ushort8_t o;
    o[0] = f2bf(vout[8 * k + 0] + xa.x);
    o[1] = f2bf(vout[8 * k + 1] + xa.y);
    o[2] = f2bf(vout[8 * k + 2] + xa.z);
    o[3] = f2bf(vout[8 * k + 3] + xa.w);
    o[4] = f2bf(vout[8 * k + 4] + xb4.x);
    o[5] = f2bf(vout[8 * k + 5] + xb4.y);
    o[6] = f2bf(vout[8 * k + 6] + xb4.z);
    o[7] = f2bf(vout[8 * k + 7] + xb4.w);
    yr[k] = o;
  }
}

// ---------------------------------------------------------------------------
// launch
// ---------------------------------------------------------------------------
extern "C" void kernel_launch(void* const* d_in, const int* in_sizes, int n_in,
                              void* d_out, int out_size, void* d_ws, size_t ws_size,
                              hipStream_t stream) {
  const float* x = (const float*)d_in[0];
  const float* qkv_w = (const float*)d_in[1];
  const float* proj_w = (const float*)d_in[2];
  const float* proj_b = (const float*)d_in[3];
  float* out = (float*)d_out;

  char* ws = (char*)d_ws;
  // ws layout (bytes), total 206,045,184:
  //   [0, 50331648)            xb [M][768] bf16  -> reused as y [M][768] bf16
  //   [50331648, 201326592)    qkvT [2304][M] bf16
  //   [201326592, 204865536)   wqkvb [2304][768] bf16 (absorbs OOB tap reads)
  //   [204865536, 206045184)   wprojb [768][768] bf16
  __hip_bfloat16* xb = (__hip_bfloat16*)(ws);
  __hip_bfloat16* qkvT = (__hip_bfloat16*)(ws + 50331648);
  __hip_bfloat16* wqkvb = (__hip_bfloat16*)(ws + 201326592);
  __hip_bfloat16* wprojb = (__hip_bfloat16*)(ws + 204865536);
  __hip_bfloat16* ybuf = xb;                   // after GEMM1 consumed xb

  cvt_kernel<<<(MM * CC / 4 + 255) / 256, 256, 0, stream>>>(x, xb, MM * CC / 4);
  cvt_kernel<<<(NQKV * CC / 4 + 255) / 256, 256, 0, stream>>>(qkv_w, wqkvb, NQKV * CC / 4);
  cvt_kernel<<<(CC * CC / 4 + 255) / 256, 256, 0, stream>>>(proj_w, wprojb, CC * CC / 4);

  // qkv GEMM -> channel-major qkvT [2304][M]   (grid 4608 % 8 == 0)
  gemm_bf16_kernel<1><<<(MM / 128) * (NQKV / 128), 256, 0, stream>>>(
      xb, wqkvb, (void*)qkvT, nullptr, MM, NQKV, CC);

  // attention + residual -> y [M][768] bf16 (pixel-major, fused transpose)
  attn_kernel<<<12 * 128, 256, 0, stream>>>(
      (const unsigned short*)qkvT, x, (unsigned short*)ybuf);

  // proj GEMM -> f32 out [M][768] + bias      (grid 1536 % 8 == 0)
  gemm_bf16_kernel<2><<<(MM / 128) * (CC / 128), 256, 0, stream>>>(
      ybuf, wprojb, (void*)out, proj_b, MM, CC, CC);
}

// Round 5
// 385.654 us; speedup vs baseline: 1.7385x; 1.0816x over previous
//
#include <hip/hip_runtime.h>
#include <hip/hip_bf16.h>

// Problem constants
#define CC 768
#define MM 32768                // pixels (8*64*64)
#define NQKV 2304               // 3*CC
#define SCALE_ 0.125f           // 64^-0.5

typedef __bf16 bf16x8 __attribute__((ext_vector_type(8)));
typedef float f32x4 __attribute__((ext_vector_type(4)));
typedef unsigned short ushort8_t __attribute__((ext_vector_type(8)));

static __device__ __forceinline__ float bf2f(unsigned short u) {
  return __uint_as_float(((unsigned int)u) << 16);
}
static __device__ __forceinline__ unsigned short f2bf(float f) {
  __hip_bfloat16 t = __float2bfloat16(f);
  return __builtin_bit_cast(unsigned short, t);
}

// ---------------------------------------------------------------------------
// f32 -> bf16 convert (vectorized float4 -> 4x bf16)
// ---------------------------------------------------------------------------
__global__ void cvt_kernel(const float* __restrict__ in,
                           __hip_bfloat16* __restrict__ out, int n4) {
  int i = blockIdx.x * blockDim.x + threadIdx.x;
  if (i >= n4) return;
  float4 v = reinterpret_cast<const float4*>(in)[i];
  ushort4 o;
  o.x = f2bf(v.x); o.y = f2bf(v.y); o.z = f2bf(v.z); o.w = f2bf(v.w);
  reinterpret_cast<ushort4*>(out)[i] = o;
}

// ---------------------------------------------------------------------------
// bf16 GEMM: D = A[M][K] * Bw[N][K]^T. 128x128 tile, BK=32, 4 waves (2x2).
// Depth-2 counted-vmcnt pipeline (T3+T4), 3 LDS buffer sets, conflict-free
// swizzled staging (rule #21). XCD-aware block swizzle. UNCHANGED from R4.
// MODE 1: store bf16 TRANSPOSED outT[N][M]; MODE 2: f32 out[M][N] + bias.
// ---------------------------------------------------------------------------
template <int MODE>
__global__ __launch_bounds__(256) void gemm_bf16_kernel(
    const __hip_bfloat16* __restrict__ A,
    const __hip_bfloat16* __restrict__ Bw,
    void* __restrict__ outp,
    const float* __restrict__ bias,
    int M, int N, int K) {
  __shared__ __hip_bfloat16 lA[3][128 * 32];
  __shared__ __hip_bfloat16 lB[3][128 * 32];

  const int nBN = N >> 7;
  const int cpx = gridDim.x >> 3;                 // chunks per XCD (grid%8==0)
  const int bid = ((int)blockIdx.x & 7) * cpx + ((int)blockIdx.x >> 3);
  const int bm = bid / nBN;
  const int bn = bid % nBN;
  const int tid = threadIdx.x;
  const int lane = tid & 63;
  const int wv = tid >> 6;
  const int wr = wv >> 1;
  const int wc = wv & 1;

  f32x4 acc[4][4] = {};

  const int srow = wv * 16 + (lane >> 2);
  const int scol = ((lane & 3) ^ ((lane >> 3) & 3)) * 8;   // swizzled source
  const size_t Abase = (size_t)(bm * 128) * K;
  const size_t Bbase = (size_t)(bn * 128) * K;

  const int frow = lane & 15;
  const int g = lane >> 4;
  const int fcol = (g ^ ((frow >> 1) & 3)) * 8;            // matching read XOR

  auto stage = [&](int buf, int t) {
    const int k0 = t << 5;
#pragma unroll
    for (int c = 0; c < 2; ++c) {
      const __hip_bfloat16* gA = A + Abase + (size_t)(c * 64 + srow) * K + k0 + scol;
      __hip_bfloat16* sA = &lA[buf][(c * 64 + wv * 16) * 32];
      __builtin_amdgcn_global_load_lds(
          (const __attribute__((address_space(1))) void*)gA,
          (__attribute__((address_space(3))) void*)sA, 16, 0, 0);
      const __hip_bfloat16* gB = Bw + Bbase + (size_t)(c * 64 + srow) * K + k0 + scol;
      __hip_bfloat16* sB = &lB[buf][(c * 64 + wv * 16) * 32];
      __builtin_amdgcn_global_load_lds(
          (const __attribute__((address_space(1))) void*)gB,
          (__attribute__((address_space(3))) void*)sB, 16, 0, 0);
    }
  };

  const int nt = K >> 5;                     // 24 here
  stage(0, 0);
  if (nt > 1) stage(1, 1);

  int rd = 0;
  int st = 2;
  for (int t = 0; t < nt; ++t) {
    if (t + 1 < nt) asm volatile("s_waitcnt vmcnt(4)" ::: "memory");
    else            asm volatile("s_waitcnt vmcnt(0)" ::: "memory");
    __builtin_amdgcn_s_barrier();
    asm volatile("" ::: "memory");

    bf16x8 af[4], bfr[4];
#pragma unroll
    for (int m = 0; m < 4; ++m)
      af[m] = *reinterpret_cast<const bf16x8*>(&lA[rd][(wr * 64 + m * 16 + frow) * 32 + fcol]);
#pragma unroll
    for (int n = 0; n < 4; ++n)
      bfr[n] = *reinterpret_cast<const bf16x8*>(&lB[rd][(wc * 64 + n * 16 + frow) * 32 + fcol]);

    if (t + 2 < nt) stage(st, t + 2);

#pragma unroll
    for (int m = 0; m < 4; ++m)
#pragma unroll
      for (int n = 0; n < 4; ++n)
        acc[m][n] = __builtin_amdgcn_mfma_f32_16x16x32_bf16(af[m], bfr[n], acc[m][n], 0, 0, 0);

    rd = (rd == 2) ? 0 : rd + 1;
    st = (st == 2) ? 0 : st + 1;
  }

  // C/D layout: col = lane&15, row = (lane>>4)*4 + r   [m89]
  const int r0 = (lane >> 4) * 4;
  const int cc_ = lane & 15;
#pragma unroll
  for (int m = 0; m < 4; ++m) {
#pragma unroll
    for (int n = 0; n < 4; ++n) {
      const int grow = bm * 128 + wr * 64 + m * 16 + r0;
      const int gcol = bn * 128 + wc * 64 + n * 16 + cc_;
      if (MODE == 1) {
        __hip_bfloat16* outT = (__hip_bfloat16*)outp;
        ushort4 pk;
        pk.x = f2bf(acc[m][n][0]);
        pk.y = f2bf(acc[m][n][1]);
        pk.z = f2bf(acc[m][n][2]);
        pk.w = f2bf(acc[m][n][3]);
        *reinterpret_cast<ushort4*>(outT + (size_t)gcol * M + grow) = pk;
      } else {
        float* outF = (float*)outp;
        const float bv = bias ? bias[gcol] : 0.f;
#pragma unroll
        for (int r = 0; r < 4; ++r)
          outF[(size_t)(grow + r) * N + gcol] = acc[m][n][r] + bv;
      }
    }
  }
}

// ---------------------------------------------------------------------------
// Dilated local attention v3: thread = (pixel, head, half).
//  - channel-split x2: vout[32] (was 64) -> lower VGPR, 2x waves (12288)
//  - explicit load batching (4 channels/batch): ~40 independent ushort loads
//    issued before their FMAs -> deep VMEM pipelining per wave
//  - residual read from bf16 xb (not f32 x): halves residual HBM traffic;
//    y aliases xb with exclusive per-thread (pixel, ch-range) ownership
// QK logits are computed redundantly by both halves (cache-hot).
// OOB taps: logit 0 in denom path, weight 0 in numerator (zero-pad ref).
// OOB reads land inside workspace (adjacent planes / weight region).
// ---------------------------------------------------------------------------
__global__ __launch_bounds__(256) void attn_kernel(
    const unsigned short* __restrict__ qkvT,
    const unsigned short* __restrict__ xres,
    unsigned short* __restrict__ y) {
  const int hh = blockIdx.x >> 7;              // 0..23 (uniform per block)
  const int head = hh >> 1;
  const int half = hh & 1;
  const int p = ((blockIdx.x & 127) << 8) + threadIdx.x;  // pixel
  const int h = (p >> 6) & 63;
  const int w = p & 63;
  const int grp = head >> 2;
  const int dil = grp + 1;                     // DILATIONS = (1,2,3)
  const int chq = grp * 256 + (head & 3) * 64;

  int voff[9];
  bool valid[9];
#pragma unroll
  for (int t = 0; t < 9; ++t) {
    const int di = t / 3 - 1, dj = t % 3 - 1;
    valid[t] = ((unsigned)(h + di * dil) < 64u) && ((unsigned)(w + dj * dil) < 64u);
    voff[t] = p + (di * 64 + dj) * dil + 256;  // +256 bias keeps index >= 0
  }
  const int voffq = p + 256;

  // ---- QK phase: full 64-dim dot, batched 4 channels at a time ----
  const unsigned short* qb = qkvT + (size_t)chq * MM - 256;
  const unsigned short* kb = qkvT + (size_t)(768 + chq) * MM - 256;

  float l[9] = {};
#pragma unroll 1
  for (int cb = 0; cb < 16; ++cb) {
    unsigned short qv[4];
    unsigned short kv[4][9];
#pragma unroll
    for (int i = 0; i < 4; ++i) qv[i] = qb[voffq + i * MM];
#pragma unroll
    for (int i = 0; i < 4; ++i)
#pragma unroll
      for (int t = 0; t < 9; ++t) kv[i][t] = kb[voff[t] + i * MM];
#pragma unroll
    for (int i = 0; i < 4; ++i) {
      const float qf = bf2f(qv[i]);
#pragma unroll
      for (int t = 0; t < 9; ++t)
        l[t] = fmaf(qf, bf2f(kv[i][t]), l[t]);
    }
    qb += 4 * MM;
    kb += 4 * MM;
  }

#pragma unroll
  for (int t = 0; t < 9; ++t) l[t] = valid[t] ? l[t] * SCALE_ : 0.f;
  float mx = l[0];
#pragma unroll
  for (int t = 1; t < 9; ++t) mx = fmaxf(mx, l[t]);
  float den = 0.f;
#pragma unroll
  for (int t = 0; t < 9; ++t) {
    const float e = __expf(l[t] - mx);
    den += e;                                  // invalid taps count in denom
    l[t] = valid[t] ? e : 0.f;                 // but contribute 0 to numerator
  }
  const float inv = 1.f / den;
#pragma unroll
  for (int t = 0; t < 9; ++t) l[t] *= inv;

  // ---- PV phase: this half's 32 channels, batched 4 at a time ----
  const int cho = chq + half * 32;
  const unsigned short* vb = qkvT + (size_t)(1536 + cho) * MM - 256;
  float vout[32];
#pragma unroll 1
  for (int cb = 0; cb < 8; ++cb) {
    unsigned short vv[4][9];
#pragma unroll
    for (int i = 0; i < 4; ++i)
#pragma unroll
      for (int t = 0; t < 9; ++t) vv[i][t] = vb[voff[t] + i * MM];
#pragma unroll
    for (int i = 0; i < 4; ++i) {
      float acc = 0.f;
#pragma unroll
      for (int t = 0; t < 9; ++t)
        acc = fmaf(l[t], bf2f(vv[i][t]), acc);
      vout[cb * 4 + i] = acc;
    }
    vb += 4 * MM;
  }

  // ---- residual (bf16) + pack + store: 4 x 16B contiguous per thread ----
  const ushort8_t* xr = reinterpret_cast<const ushort8_t*>(xres + (size_t)p * CC + cho);
  ushort8_t* yr = reinterpret_cast<ushort8_t*>(y + (size_t)p * CC + cho);
#pragma unroll
  for (int k = 0; k < 4; ++k) {
    const ushort8_t xa = xr[k];
    ushort8_t o;
#pragma unroll
    for (int j = 0; j < 8; ++j)
      o[j] = f2bf(vout[8 * k + j] + bf2f(xa[j]));
    yr[k] = o;
  }
}

// ---------------------------------------------------------------------------
// launch
// ---------------------------------------------------------------------------
extern "C" void kernel_launch(void* const* d_in, const int* in_sizes, int n_in,
                              void* d_out, int out_size, void* d_ws, size_t ws_size,
                              hipStream_t stream) {
  const float* x = (const float*)d_in[0];
  const float* qkv_w = (const float*)d_in[1];
  const float* proj_w = (const float*)d_in[2];
  const float* proj_b = (const float*)d_in[3];
  float* out = (float*)d_out;

  char* ws = (char*)d_ws;
  // ws layout (bytes), total 206,045,184:
  //   [0, 50331648)            xb [M][768] bf16  -> reused as y [M][768] bf16
  //   [50331648, 201326592)    qkvT [2304][M] bf16
  //   [201326592, 204865536)   wqkvb [2304][768] bf16 (absorbs OOB tap reads)
  //   [204865536, 206045184)   wprojb [768][768] bf16
  __hip_bfloat16* xb = (__hip_bfloat16*)(ws);
  __hip_bfloat16* qkvT = (__hip_bfloat16*)(ws + 50331648);
  __hip_bfloat16* wqkvb = (__hip_bfloat16*)(ws + 201326592);
  __hip_bfloat16* wprojb = (__hip_bfloat16*)(ws + 204865536);
  __hip_bfloat16* ybuf = xb;                   // y overwrites xb (per-thread
                                               // read-then-write, exclusive)

  cvt_kernel<<<(MM * CC / 4 + 255) / 256, 256, 0, stream>>>(x, xb, MM * CC / 4);
  cvt_kernel<<<(NQKV * CC / 4 + 255) / 256, 256, 0, stream>>>(qkv_w, wqkvb, NQKV * CC / 4);
  cvt_kernel<<<(CC * CC / 4 + 255) / 256, 256, 0, stream>>>(proj_w, wprojb, CC * CC / 4);

  // qkv GEMM -> channel-major qkvT [2304][M]   (grid 4608 % 8 == 0)
  gemm_bf16_kernel<1><<<(MM / 128) * (NQKV / 128), 256, 0, stream>>>(
      xb, wqkvb, (void*)qkvT, nullptr, MM, NQKV, CC);

  // attention + residual -> y [M][768] bf16 (24 head-halves x 128 pixel-blocks)
  attn_kernel<<<24 * 128, 256, 0, stream>>>(
      (const unsigned short*)qkvT, (const unsigned short*)xb,
      (unsigned short*)ybuf);

  // proj GEMM -> f32 out [M][768] + bias      (grid 1536 % 8 == 0)
  gemm_bf16_kernel<2><<<(MM / 128) * (CC / 128), 256, 0, stream>>>(
      ybuf, wprojb, (void*)out, proj_b, MM, CC, CC);
}